// Round 3
// baseline (1366.774 us; speedup 1.0000x reference)
//
#include <hip/hip_runtime.h>
#include <cstdint>

#define NBATCH 256
#define NT   128
#define NS   128
#define NHID 256
#define NTHR 512
#define NWG  256

typedef _Float16 f16;
typedef _Float16 f16x2 __attribute__((ext_vector_type(2)));

__device__ __forceinline__ float dot2f(f16x2 a, f16x2 b, float c) {
#if defined(__has_builtin) && __has_builtin(__builtin_amdgcn_fdot2)
  return __builtin_amdgcn_fdot2(a, b, c, false);
#else
  return c + (float)a.x * (float)b.x + (float)a.y * (float)b.y;
#endif
}
__device__ __forceinline__ f16x2 pk(float a, float b) {
  f16x2 r; r.x = (f16)a; r.y = (f16)b; return r;
}

// ws byte layout
#define EXCH_OFF 0              // uint [2 parity][128 group][2 half][256]
#define FLAG_OFF (512 * 1024)   // uint [256][16]  (one flag per 64B)

struct __align__(16) Sm {
  f16   waht[128 * 64 * 8];   // 131072 B: W_ah f16, 16B chunks XOR-swizzled by row
  f16   actw[2][128];         // wx f16
  f16   acth[2][256];         // h f16 (global k index)
  f16   hcq[2][4][136];       // [b][quarter][pos]: h in q0,q1; c in q2,q3 (f16)
  float E[2][128];            // exp(2*ipart)
  float P[2][128];            // exp(2*hpart)
  float spart[4][2][128];     // partial-sum scratch (hpart / score / ipart)
  float gacc[4][2][128];      // gate accumulators
  float cbuf[2][128];         // own-half c, fp32
  float w2a[128];
  float bah[128];
  float red[4];
};

__global__ void enc_init(uint32_t* flags) {
  int i = blockIdx.x * blockDim.x + threadIdx.x;
  if (i < 4096) flags[i] = 0u;
}

__global__ __launch_bounds__(NTHR, 2) void enc_main(
    const float* __restrict__ x,    const float* __restrict__ W_ah,
    const float* __restrict__ b_ah, const float* __restrict__ W_ai,
    const float* __restrict__ b_ai, const float* __restrict__ W_a,
    const float* __restrict__ b_a,  const float* __restrict__ W_ih,
    const float* __restrict__ W_hh, const float* __restrict__ b_ih,
    const float* __restrict__ b_hh, float* __restrict__ out_iw,
    float* __restrict__ out_ie,     char* __restrict__ ws)
{
  __shared__ Sm sm;
  const int tid   = threadIdx.x;
  const int wg    = blockIdx.x;
  const int group = (wg & 7) | ((wg >> 4) << 3);   // pair partner = wg^8 (same XCD if round-robin)
  const int kside = (wg >> 3) & 1;                 // which k-half this wg owns
  const int b0    = group * 2;
  const int kbase = kside * 128;

  uint32_t* exch  = (uint32_t*)(ws + EXCH_OFF);
  uint32_t* flags = (uint32_t*)(ws + FLAG_OFF);
  uint32_t* myflag = flags + (group * 2 + kside) * 16;
  uint32_t* pflag  = flags + (group * 2 + (1 - kside)) * 16;

  // ---- gate-row weights into registers (1 row per thread, f16) ----
  const int gsel = tid >> 7, kl7 = tid & 127;
  const int Rrow = gsel * 256 + kbase + kl7;
  f16x2 wxw[64];
  f16x2 whh[128];
  {
    const float4* a = (const float4*)(W_ih + (size_t)Rrow * 128);
    #pragma unroll
    for (int j = 0; j < 32; ++j) { float4 v = a[j]; wxw[2*j] = pk(v.x, v.y); wxw[2*j+1] = pk(v.z, v.w); }
    const float4* b = (const float4*)(W_hh + (size_t)Rrow * 256);
    #pragma unroll
    for (int j = 0; j < 64; ++j) { float4 v = b[j]; whh[2*j] = pk(v.x, v.y); whh[2*j+1] = pk(v.z, v.w); }
  }
  const float bias_r = b_ih[Rrow] + b_hh[Rrow];

  // ---- stage W_ah into LDS (f16, swizzled 16B chunks) ----
  for (int idx = tid; idx < 128 * 64; idx += NTHR) {
    int r = idx >> 6, c8 = idx & 63;
    const float4* s = (const float4*)(W_ah + r * 512 + c8 * 8);
    float4 v0 = s[0], v1 = s[1];
    f16x2 t4[4] = { pk(v0.x, v0.y), pk(v0.z, v0.w), pk(v1.x, v1.y), pk(v1.z, v1.w) };
    *(float4*)&sm.waht[(size_t)((r << 6) | (c8 ^ (r & 7))) * 8] = *(float4*)t4;
  }
  if (tid < 128) { sm.w2a[tid] = 2.f * W_a[tid]; sm.bah[tid] = b_ah[tid]; }
  if (tid == 0) { float s = b_a[0]; for (int i = 0; i < 128; ++i) s += W_a[i]; sm.red[0] = s; }
  for (int idx = tid; idx < 1088; idx += NTHR) ((f16*)sm.hcq)[idx] = (f16)0.f;
  if (tid < 512) ((f16*)sm.acth)[tid] = (f16)0.f;
  if (tid < 256) sm.cbuf[tid >> 7][tid & 127] = 0.f;

  // ---- ipart -> E (time-invariant) ----
  {
    const int n = tid & 127, q2 = tid >> 7;
    float a0 = 0.f, a1 = 0.f;
    const float* x0 = x + (size_t)b0 * NT * NS;
    const float* x1 = x + (size_t)(b0 + 1) * NT * NS;
    for (int tt = q2 * 32; tt < q2 * 32 + 32; ++tt) {
      float w = W_ai[tt];
      a0 = fmaf(x0[tt * NS + n], w, a0);
      a1 = fmaf(x1[tt * NS + n], w, a1);
    }
    sm.spart[q2][0][n] = a0; sm.spart[q2][1][n] = a1;
  }
  __syncthreads();
  if (tid < 256) {
    int bb = tid >> 7, n = tid & 127;
    float ip = sm.spart[0][bb][n] + sm.spart[1][bb][n] +
               sm.spart[2][bb][n] + sm.spart[3][bb][n] + b_ai[0];
    sm.E[bb][n] = __expf(2.f * ip);
  }
  __syncthreads();
  const float S0 = sm.red[0];

  for (int t = 0; t < NT; ++t) {
    // ---------- hpart: P[b][r] = exp(2*(W_ah[r,:]·[h|c] + bah[r])) ----------
    {
      const int r = tid & 127, q = tid >> 7;
      float hp0 = 0.f, hp1 = 0.f;
      #pragma unroll
      for (int i = 0; i < 16; ++i) {
        int c8 = q * 16 + i;
        float4 w4 = *(const float4*)&sm.waht[(size_t)((r << 6) | (c8 ^ (r & 7))) * 8];
        float4 a4 = *(const float4*)&sm.hcq[0][q][i * 8];
        float4 b4 = *(const float4*)&sm.hcq[1][q][i * 8];
        const f16x2* wp = (const f16x2*)&w4;
        const f16x2* ap = (const f16x2*)&a4;
        const f16x2* bp = (const f16x2*)&b4;
        #pragma unroll
        for (int u = 0; u < 4; ++u) { hp0 = dot2f(wp[u], ap[u], hp0); hp1 = dot2f(wp[u], bp[u], hp1); }
      }
      sm.spart[q][0][r] = hp0; sm.spart[q][1][r] = hp1;
    }
    __syncthreads();  // s1
    if (tid < 256) {
      int bb = tid >> 7, r = tid & 127;
      float hp = sm.spart[0][bb][r] + sm.spart[1][bb][r] + sm.spart[2][bb][r] + sm.spart[3][bb][r];
      sm.P[bb][r] = __expf(2.f * (hp + sm.bah[r]));
    }
    __syncthreads();  // s2
    // ---------- score partials ----------
    {
      const int n = tid & 127, q2 = tid >> 7;
      float e0 = sm.E[0][n], e1 = sm.E[1][n];
      float s0 = 0.f, s1 = 0.f;
      #pragma unroll 8
      for (int tt = q2 * 32; tt < q2 * 32 + 32; ++tt) {
        float w = sm.w2a[tt];
        float p0 = sm.P[0][tt], p1 = sm.P[1][tt];
        s0 = fmaf(w, __builtin_amdgcn_rcpf(fmaf(p0, e0, 1.f)), s0);
        s1 = fmaf(w, __builtin_amdgcn_rcpf(fmaf(p1, e1, 1.f)), s1);
      }
      sm.spart[q2][0][n] = s0; sm.spart[q2][1][n] = s1;
    }
    __syncthreads();  // s3
    // ---------- softmax + wx (2 waves) ----------
    if (tid < 128) {
      int bb = tid >> 6, l = tid & 63;
      float sA = S0 - (sm.spart[0][bb][l] + sm.spart[1][bb][l] + sm.spart[2][bb][l] + sm.spart[3][bb][l]);
      float sB = S0 - (sm.spart[0][bb][l+64] + sm.spart[1][bb][l+64] + sm.spart[2][bb][l+64] + sm.spart[3][bb][l+64]);
      float m = fmaxf(sA, sB);
      #pragma unroll
      for (int o = 32; o; o >>= 1) m = fmaxf(m, __shfl_xor(m, o));
      float eA = __expf(sA - m), eB = __expf(sB - m);
      float ssum = eA + eB;
      #pragma unroll
      for (int o = 32; o; o >>= 1) ssum += __shfl_xor(ssum, o);
      float rs = 1.f / ssum;
      const float* xb = x + ((size_t)(b0 + bb) * NT + t) * NS;
      float wxA = eA * rs * xb[l], wxB = eB * rs * xb[l + 64];
      sm.actw[bb][l] = (f16)wxA; sm.actw[bb][l + 64] = (f16)wxB;
      if (kside == 0) {
        float* ow = out_iw + ((size_t)(b0 + bb) * NT + t) * NS;
        ow[l] = wxA; ow[l + 64] = wxB;
      }
    }
    __syncthreads();  // s4
    // ---------- gates: own row · [wx|h] per batch (weights in registers) ----------
    {
      float a0 = bias_r, a1 = bias_r;
      #pragma unroll
      for (int j = 0; j < 16; ++j) {
        float4 r0 = *(const float4*)&sm.actw[0][j * 8];
        float4 r1 = *(const float4*)&sm.actw[1][j * 8];
        const f16x2* p0 = (const f16x2*)&r0;
        const f16x2* p1 = (const f16x2*)&r1;
        #pragma unroll
        for (int u = 0; u < 4; ++u) { a0 = dot2f(wxw[j*4+u], p0[u], a0); a1 = dot2f(wxw[j*4+u], p1[u], a1); }
      }
      #pragma unroll
      for (int j = 0; j < 32; ++j) {
        float4 r0 = *(const float4*)&sm.acth[0][j * 8];
        float4 r1 = *(const float4*)&sm.acth[1][j * 8];
        const f16x2* p0 = (const f16x2*)&r0;
        const f16x2* p1 = (const f16x2*)&r1;
        #pragma unroll
        for (int u = 0; u < 4; ++u) { a0 = dot2f(whh[j*4+u], p0[u], a0); a1 = dot2f(whh[j*4+u], p1[u], a1); }
      }
      sm.gacc[gsel][0][kl7] = a0; sm.gacc[gsel][1][kl7] = a1;
    }
    __syncthreads();  // s5
    // ---------- LSTM pointwise + exchange write ----------
    if (tid < 256) {
      int bb = tid >> 7, kl = tid & 127;
      float gi = sm.gacc[0][bb][kl], gf = sm.gacc[1][bb][kl];
      float gg = sm.gacc[2][bb][kl], go = sm.gacc[3][bb][kl];
      float ii = 1.f / (1.f + __expf(-gi));
      float ff = 1.f / (1.f + __expf(-gf));
      float gt = 1.f - 2.f / (1.f + __expf(2.f * gg));
      float oo = 1.f / (1.f + __expf(-go));
      float c2 = ff * sm.cbuf[bb][kl] + ii * gt;
      float h2 = oo * (1.f - 2.f / (1.f + __expf(2.f * c2)));
      sm.cbuf[bb][kl] = c2;
      f16 h2f = (f16)h2, c2f = (f16)c2;
      sm.acth[bb][kbase + kl] = h2f;
      sm.hcq[bb][kside][kl] = h2f;
      sm.hcq[bb][2 + kside][kl] = c2f;
      out_ie[((size_t)(b0 + bb) * NT + t) * NHID + kbase + kl] = h2;
      f16x2 pv; pv.x = h2f; pv.y = c2f;
      uint32_t v = __builtin_bit_cast(uint32_t, pv);
      uint32_t* dst = exch + (size_t)(((t & 1) * 128 + group) * 2 + kside) * 256 + tid;
      __hip_atomic_store(dst, v, __ATOMIC_RELAXED, __HIP_MEMORY_SCOPE_AGENT);
    }
    __syncthreads();  // s6 (barrier drain => exch stores at coherence point)
    if (tid == 0) {
      __hip_atomic_store(myflag, (uint32_t)(t + 1), __ATOMIC_RELAXED, __HIP_MEMORY_SCOPE_AGENT);
      while (__hip_atomic_load(pflag, __ATOMIC_RELAXED, __HIP_MEMORY_SCOPE_AGENT) < (uint32_t)(t + 1))
        __builtin_amdgcn_s_sleep(1);
    }
    __syncthreads();  // s7
    if (tid < 256) {
      int bb = tid >> 7, kl = tid & 127;
      uint32_t v = __hip_atomic_load(
          exch + (size_t)(((t & 1) * 128 + group) * 2 + (1 - kside)) * 256 + tid,
          __ATOMIC_RELAXED, __HIP_MEMORY_SCOPE_AGENT);
      f16x2 pv = __builtin_bit_cast(f16x2, v);
      sm.acth[bb][(1 - kside) * 128 + kl] = pv.x;
      sm.hcq[bb][1 - kside][kl] = pv.x;
      sm.hcq[bb][2 + (1 - kside)][kl] = pv.y;
    }
    __syncthreads();  // s8
  }
}

extern "C" void kernel_launch(void* const* d_in, const int* in_sizes, int n_in,
                              void* d_out, int out_size, void* d_ws, size_t ws_size,
                              hipStream_t stream) {
  const float* x    = (const float*)d_in[0];
  const float* W_ah = (const float*)d_in[1];
  const float* b_ah = (const float*)d_in[2];
  const float* W_ai = (const float*)d_in[3];
  const float* b_ai = (const float*)d_in[4];
  const float* W_a  = (const float*)d_in[5];
  const float* b_a  = (const float*)d_in[6];
  const float* W_ih = (const float*)d_in[7];
  const float* W_hh = (const float*)d_in[8];
  const float* b_ih = (const float*)d_in[9];
  const float* b_hh = (const float*)d_in[10];
  float* out_iw = (float*)d_out;
  float* out_ie = (float*)d_out + (size_t)NBATCH * NT * NS;
  char* ws = (char*)d_ws;

  hipLaunchKernelGGL(enc_init, dim3(8), dim3(512), 0, stream, (uint32_t*)(ws + FLAG_OFF));
  hipLaunchKernelGGL(enc_main, dim3(NWG), dim3(NTHR), 0, stream,
                     x, W_ah, b_ah, W_ai, b_ai, W_a, b_a, W_ih, W_hh, b_ih, b_hh,
                     out_iw, out_ie, ws);
}